// Round 1
// 930.052 us; speedup vs baseline: 1.0929x; 1.0929x over previous
//
#include <hip/hip_runtime.h>

#define B_  2
#define S_  2048
#define D_  1024
#define H_  16
#define DH_ 64

typedef _Float16 f16x8 __attribute__((ext_vector_type(8)));
typedef float    f32x4 __attribute__((ext_vector_type(4)));

#define MFMA16(a, b, c) __builtin_amdgcn_mfma_f32_16x16x32_f16((a), (b), (c), 0, 0, 0)

// width-16 async global->LDS (guide §5: compiler never auto-emits this)
#define GLD16(gptr, lptr)                                                           \
    __builtin_amdgcn_global_load_lds(                                               \
        (const __attribute__((address_space(1))) void*)(gptr),                      \
        (__attribute__((address_space(3))) void*)(lptr), 16, 0, 0)

// ---------------------------------------------------------------------------
// Prep 1: fp32 -> fp16 elementwise for q_in/k_in/v_in (layout preserved).
// ---------------------------------------------------------------------------
__global__ __launch_bounds__(256) void cvt_x(
    const float* __restrict__ q, const float* __restrict__ k, const float* __restrict__ v,
    _Float16* __restrict__ x16)   // q16|k16|v16 contiguous, 4M halfs each
{
    const int z = blockIdx.y;
    const float* src = (z == 0) ? q : (z == 1) ? k : v;
    _Float16* dst = x16 + (size_t)z * (4096 * 1024);
    const size_t i = ((size_t)blockIdx.x * 256 + threadIdx.x) * 8;
    float4 a = *(const float4*)(src + i);
    float4 b = *(const float4*)(src + i + 4);
    f16x8 o = { (_Float16)a.x, (_Float16)a.y, (_Float16)a.z, (_Float16)a.w,
                (_Float16)b.x, (_Float16)b.y, (_Float16)b.z, (_Float16)b.w };
    *(f16x8*)(dst + i) = o;
}

// ---------------------------------------------------------------------------
// Prep 2: convert + transpose weights: Wt[n][k] = (fp16)W[k][n].  64x64 tiles.
// ---------------------------------------------------------------------------
__global__ __launch_bounds__(256) void cvt_w(
    const float* __restrict__ Wq, const float* __restrict__ Wk,
    const float* __restrict__ Wv, const float* __restrict__ Wo,
    _Float16* __restrict__ Wt3,   // Wq^T|Wk^T|Wv^T contiguous (1M halfs each)
    _Float16* __restrict__ Wot)   // Wo^T (must outlive attn -> lives in ws)
{
    const int z = blockIdx.z;
    const float* W = (z == 0) ? Wq : (z == 1) ? Wk : (z == 2) ? Wv : Wo;
    _Float16* Wt = (z < 3) ? (Wt3 + (size_t)z * (1024 * 1024)) : Wot;

    __shared__ _Float16 T[64][72];
    const int k0 = blockIdx.y * 64, n0 = blockIdx.x * 64;
    const int r = threadIdx.x >> 3, c8 = (threadIdx.x & 7) * 8;

#pragma unroll
    for (int it = 0; it < 2; ++it) {
        const int row = it * 32 + r;
        const float* p = W + (size_t)(k0 + row) * D_ + n0 + c8;
        float4 a = *(const float4*)p;
        float4 b = *(const float4*)(p + 4);
        _Float16* t = &T[row][c8];
        t[0] = (_Float16)a.x; t[1] = (_Float16)a.y; t[2] = (_Float16)a.z; t[3] = (_Float16)a.w;
        t[4] = (_Float16)b.x; t[5] = (_Float16)b.y; t[6] = (_Float16)b.z; t[7] = (_Float16)b.w;
    }
    __syncthreads();
#pragma unroll
    for (int it = 0; it < 2; ++it) {
        const int nrow = it * 32 + r;
        f16x8 o = { T[c8 + 0][nrow], T[c8 + 1][nrow], T[c8 + 2][nrow], T[c8 + 3][nrow],
                    T[c8 + 4][nrow], T[c8 + 5][nrow], T[c8 + 6][nrow], T[c8 + 7][nrow] };
        *(f16x8*)(Wt + (size_t)(n0 + nrow) * D_ + k0 + c8) = o;
    }
}

// ---------------------------------------------------------------------------
// Fast GEMM (m97 structure): C = A(fp16 [M][K]) @ Bt(fp16 [N][K])^T + bias.
// 128x128 tile, BK=32, 256 threads = 4 waves (2x2), each wave 64x64 (4x4 frags).
// Staging: width-16 global_load_lds into linear LDS (no padding, required).
// gemm_qkv_f: result fp16 scattered to [b,h,s,dh].  gemm_out_f: fp32 [m][n].
// ---------------------------------------------------------------------------
__global__ __launch_bounds__(256) void gemm_qkv_f(
    const _Float16* __restrict__ X16, const _Float16* __restrict__ Wt3,
    const float* __restrict__ bq, const float* __restrict__ bk, const float* __restrict__ bv,
    _Float16* __restrict__ QKVh)
{
    const int z = blockIdx.z;
    const _Float16* Ag = X16 + (size_t)z * (4096 * 1024);
    const _Float16* Bg = Wt3 + (size_t)z * (1024 * 1024);
    const float* bias = (z == 0) ? bq : (z == 1) ? bk : bv;
    _Float16* dst = QKVh + (size_t)z * (4096 * 1024);

    __shared__ _Float16 As[128 * 32];   // 8 KB, linear [row][k]
    __shared__ _Float16 Bs[128 * 32];   // 8 KB, linear [n][k]

    const int tid = threadIdx.x, lane = tid & 63, wave = tid >> 6;
    const int quad = lane >> 4, col = lane & 15;
    const int wm = wave >> 1, wn = wave & 1;
    const int bm0 = blockIdx.y * 128, bn0 = blockIdx.x * 128;

    const int srow = lane >> 2;          // staging: row within 16-row chunk
    const int ska  = (lane & 3) * 8;     // staging: k offset (8 halfs = 16B)

    f32x4 acc[4][4] = {};

    for (int k0 = 0; k0 < D_; k0 += 32) {
#pragma unroll
        for (int i = 0; i < 2; ++i) {
            const int ch = wave * 2 + i;                 // 0..7: 16-row chunk
            const int row = ch * 16 + srow;
            GLD16(Ag + (size_t)(bm0 + row) * D_ + k0 + ska, &As[ch * 512]);
            GLD16(Bg + (size_t)(bn0 + row) * D_ + k0 + ska, &Bs[ch * 512]);
        }
        __syncthreads();

        f16x8 a[4], b[4];
#pragma unroll
        for (int r = 0; r < 4; ++r)
            a[r] = *(const f16x8*)&As[(wm * 64 + r * 16 + col) * 32 + quad * 8];
#pragma unroll
        for (int c = 0; c < 4; ++c)
            b[c] = *(const f16x8*)&Bs[(wn * 64 + c * 16 + col) * 32 + quad * 8];
#pragma unroll
        for (int r = 0; r < 4; ++r)
#pragma unroll
            for (int c = 0; c < 4; ++c)
                acc[r][c] = MFMA16(a[r], b[c], acc[r][c]);
        __syncthreads();
    }

#pragma unroll
    for (int r = 0; r < 4; ++r)
#pragma unroll
        for (int c = 0; c < 4; ++c) {
            const int n = bn0 + wn * 64 + c * 16 + col;
            const int h = n >> 6, dh = n & 63;
            const float bi = bias[n];
#pragma unroll
            for (int e = 0; e < 4; ++e) {
                const int m = bm0 + wm * 64 + r * 16 + quad * 4 + e;
                const int bb = m >> 11, s = m & 2047;
                dst[(((size_t)(bb * H_ + h)) * S_ + s) * DH_ + dh] =
                    (_Float16)(acc[r][c][e] + bi);
            }
        }
}

__global__ __launch_bounds__(256) void gemm_out_f(
    const _Float16* __restrict__ Ag, const _Float16* __restrict__ Bg,
    const float* __restrict__ bias, float* __restrict__ out)
{
    __shared__ _Float16 As[128 * 32];
    __shared__ _Float16 Bs[128 * 32];

    const int tid = threadIdx.x, lane = tid & 63, wave = tid >> 6;
    const int quad = lane >> 4, col = lane & 15;
    const int wm = wave >> 1, wn = wave & 1;
    const int bm0 = blockIdx.y * 128, bn0 = blockIdx.x * 128;

    const int srow = lane >> 2;
    const int ska  = (lane & 3) * 8;

    f32x4 acc[4][4] = {};

    for (int k0 = 0; k0 < D_; k0 += 32) {
#pragma unroll
        for (int i = 0; i < 2; ++i) {
            const int ch = wave * 2 + i;
            const int row = ch * 16 + srow;
            GLD16(Ag + (size_t)(bm0 + row) * D_ + k0 + ska, &As[ch * 512]);
            GLD16(Bg + (size_t)(bn0 + row) * D_ + k0 + ska, &Bs[ch * 512]);
        }
        __syncthreads();

        f16x8 a[4], b[4];
#pragma unroll
        for (int r = 0; r < 4; ++r)
            a[r] = *(const f16x8*)&As[(wm * 64 + r * 16 + col) * 32 + quad * 8];
#pragma unroll
        for (int c = 0; c < 4; ++c)
            b[c] = *(const f16x8*)&Bs[(wn * 64 + c * 16 + col) * 32 + quad * 8];
#pragma unroll
        for (int r = 0; r < 4; ++r)
#pragma unroll
            for (int c = 0; c < 4; ++c)
                acc[r][c] = MFMA16(a[r], b[c], acc[r][c]);
        __syncthreads();
    }

#pragma unroll
    for (int r = 0; r < 4; ++r)
#pragma unroll
        for (int c = 0; c < 4; ++c) {
            const int n = bn0 + wn * 64 + c * 16 + col;
            const float bi = bias[n];
#pragma unroll
            for (int e = 0; e < 4; ++e) {
                const int m = bm0 + wm * 64 + r * 16 + quad * 4 + e;
                out[(size_t)m * D_ + n] = acc[r][c][e] + bi;
            }
        }
}

// ---------------------------------------------------------------------------
// Attention: UNCHANGED from verified baseline (isolating the GEMM change).
// ---------------------------------------------------------------------------
__global__ __launch_bounds__(256) void attn_kernel(
    const _Float16* __restrict__ Qh, const _Float16* __restrict__ Kh,
    const _Float16* __restrict__ Vh, const float* __restrict__ mask,
    float* __restrict__ attn, _Float16* __restrict__ ctx)
{
    const int bh = blockIdx.y;
    const int b = bh >> 4, h = bh & 15;
    const int qb0 = blockIdx.x * 64;
    const int tid = threadIdx.x, lane = tid & 63, wave = tid >> 6;
    const int quad = lane >> 4, col = lane & 15;

    __shared__ _Float16 Ks[32][72];
    __shared__ _Float16 Vts[64][40];
    __shared__ _Float16 Ps[4][16][40];

    const int qrow0 = qb0 + wave * 16;

    const _Float16* qp = Qh + ((size_t)bh * S_ + qrow0 + col) * DH_;
    const f16x8 aq0 = *(const f16x8*)(qp + quad * 8);
    const f16x8 aq1 = *(const f16x8*)(qp + 32 + quad * 8);

    const float LOG2E = 1.4426950408889634f;
    const float scale_l2 = 0.125f * LOG2E;

    float mrow[4] = { -1e30f, -1e30f, -1e30f, -1e30f };
    float lrow[4] = { 0.f, 0.f, 0.f, 0.f };

    const int krow = tid >> 3, kc8 = (tid & 7) * 8;

    for (int kt = 0; kt < S_; kt += 32) {
        *(f16x8*)&Ks[krow][kc8] =
            *(const f16x8*)(Kh + ((size_t)bh * S_ + kt + krow) * DH_ + kc8);
        __syncthreads();
#pragma unroll
        for (int c = 0; c < 2; ++c) {
            f16x8 b0 = *(const f16x8*)&Ks[c * 16 + col][quad * 8];
            f16x8 b1 = *(const f16x8*)&Ks[c * 16 + col][32 + quad * 8];
            f32x4 sc = {};
            sc = MFMA16(aq0, b0, sc);
            sc = MFMA16(aq1, b1, sc);
#pragma unroll
            for (int e = 0; e < 4; ++e) {
                const int q = qrow0 + quad * 4 + e;
                const float s2 = sc[e] * scale_l2 +
                    mask[((size_t)b * S_ + q) * S_ + kt + c * 16 + col] * LOG2E;
                const float nm = fmaxf(mrow[e], s2);
                lrow[e] = lrow[e] * exp2f(mrow[e] - nm) + exp2f(s2 - nm);
                mrow[e] = nm;
            }
        }
        __syncthreads();
    }

#pragma unroll
    for (int off = 1; off < 16; off <<= 1) {
#pragma unroll
        for (int e = 0; e < 4; ++e) {
            const float om = __shfl_xor(mrow[e], off, 64);
            const float ol = __shfl_xor(lrow[e], off, 64);
            const float nm = fmaxf(mrow[e], om);
            lrow[e] = lrow[e] * exp2f(mrow[e] - nm) + ol * exp2f(om - nm);
            mrow[e] = nm;
        }
    }
    float invl[4];
#pragma unroll
    for (int e = 0; e < 4; ++e) invl[e] = 1.0f / lrow[e];

    f32x4 cacc[4] = {};
    for (int kt = 0; kt < S_; kt += 32) {
        *(f16x8*)&Ks[krow][kc8] =
            *(const f16x8*)(Kh + ((size_t)bh * S_ + kt + krow) * DH_ + kc8);
        {
            f16x8 v0 = *(const f16x8*)(Vh + ((size_t)bh * S_ + kt + krow) * DH_ + kc8);
#pragma unroll
            for (int j = 0; j < 8; ++j) Vts[kc8 + j][krow] = v0[j];
        }
        __syncthreads();

#pragma unroll
        for (int c = 0; c < 2; ++c) {
            f16x8 b0 = *(const f16x8*)&Ks[c * 16 + col][quad * 8];
            f16x8 b1 = *(const f16x8*)&Ks[c * 16 + col][32 + quad * 8];
            f32x4 sc = {};
            sc = MFMA16(aq0, b0, sc);
            sc = MFMA16(aq1, b1, sc);
#pragma unroll
            for (int e = 0; e < 4; ++e) {
                const int q = qrow0 + quad * 4 + e;
                const float s2 = sc[e] * scale_l2 +
                    mask[((size_t)b * S_ + q) * S_ + kt + c * 16 + col] * LOG2E;
                const float p = exp2f(s2 - mrow[e]) * invl[e];
                attn[((size_t)bh * S_ + q) * S_ + kt + c * 16 + col] = p;
                Ps[wave][quad * 4 + e][c * 16 + col] = (_Float16)p;
            }
        }

        {
            f16x8 apf = *(const f16x8*)&Ps[wave][col][quad * 8];
#pragma unroll
            for (int nt = 0; nt < 4; ++nt) {
                f16x8 bv = *(const f16x8*)&Vts[nt * 16 + col][quad * 8];
                cacc[nt] = MFMA16(apf, bv, cacc[nt]);
            }
        }
        __syncthreads();
    }

#pragma unroll
    for (int nt = 0; nt < 4; ++nt)
#pragma unroll
        for (int e = 0; e < 4; ++e) {
            const int s = qrow0 + quad * 4 + e;
            const int d = h * DH_ + nt * 16 + col;
            ctx[((size_t)b * S_ + s) * D_ + d] = (_Float16)cacc[nt][e];
        }
}

extern "C" void kernel_launch(void* const* d_in, const int* in_sizes, int n_in,
                              void* d_out, int out_size, void* d_ws, size_t ws_size,
                              hipStream_t stream) {
    const float* q_in = (const float*)d_in[0];
    const float* k_in = (const float*)d_in[1];
    const float* v_in = (const float*)d_in[2];
    const float* mask = (const float*)d_in[3];
    const float* Wq   = (const float*)d_in[4];
    const float* bq   = (const float*)d_in[5];
    const float* Wk   = (const float*)d_in[6];
    const float* bk   = (const float*)d_in[7];
    const float* Wv   = (const float*)d_in[8];
    const float* bv   = (const float*)d_in[9];
    const float* Wo   = (const float*)d_in[10];
    const float* bo   = (const float*)d_in[11];

    float* out  = (float*)d_out;
    float* attn = out + (size_t)B_ * S_ * D_;

    const size_t elems = (size_t)B_ * H_ * S_ * DH_;   // 4,194,304

    // Workspace: Qh|Kh|Vh|Ctx (8 MB each) + Wo^T (2 MB) = 34 MB.
    _Float16* Qh  = (_Float16*)d_ws;
    _Float16* Kh  = Qh + elems;
    _Float16* Vh  = Kh + elems;
    _Float16* Ctx = Vh + elems;
    _Float16* Wot = Ctx + elems;

    // Scratch in the attn output region (30 MB of 512 MB): q16|k16|v16 (24 MB)
    // + Wq^T|Wk^T|Wv^T (6 MB). Dead before attn_kernel overwrites all of attn.
    _Float16* X16 = (_Float16*)attn;
    _Float16* Wt3 = X16 + 3 * elems;

    cvt_x<<<dim3(2048, 3), 256, 0, stream>>>(q_in, k_in, v_in, X16);
    cvt_w<<<dim3(16, 16, 4), 256, 0, stream>>>(Wq, Wk, Wv, Wo, Wt3, Wot);
    gemm_qkv_f<<<dim3(8, 32, 3), 256, 0, stream>>>(X16, Wt3, bq, bk, bv, Qh);
    attn_kernel<<<dim3(32, 32), 256, 0, stream>>>(Qh, Kh, Vh, mask, attn, Ctx);
    gemm_out_f<<<dim3(8, 32), 256, 0, stream>>>(Ctx, Wot, bo, out);
}